// Round 1
// baseline (886.187 us; speedup 1.0000x reference)
//
#include <hip/hip_runtime.h>

#define NQ 2048
#define NKK 2048
#define DD 1024
#define HH 16

typedef __attribute__((ext_vector_type(8))) short bf16x8;
typedef __attribute__((ext_vector_type(4))) float f32x4;

__device__ __forceinline__ short f2bf(float f){
    union { float f; unsigned u; } v; v.f = f;
    unsigned u = v.u + 0x7FFFu + ((v.u >> 16) & 1u);
    return (short)(u >> 16);
}
__device__ __forceinline__ float bf2f(unsigned short u){
    union { unsigned u; float f; } v; v.u = ((unsigned)u) << 16;
    return v.f;
}

// ---------------- fp32 -> bf16 conversion ----------------
__global__ __launch_bounds__(256) void cvt_bf16(const float* __restrict__ src,
                                                short* __restrict__ dst, int n){
    int i = (blockIdx.x * 256 + threadIdx.x) * 4;
    if (i < n){
        float4 v = *(const float4*)(src + i);
        union { short s[4]; uint2 u; } o;
        o.s[0] = f2bf(v.x); o.s[1] = f2bf(v.y);
        o.s[2] = f2bf(v.z); o.s[3] = f2bf(v.w);
        *(uint2*)(dst + i) = o.u;
    }
}

// ---------------- XPos RoPE (elementwise, pairs) ----------------
// x,y: bf16 (B, N, D). One thread per (even,odd) pair.
__global__ __launch_bounds__(256) void rope_kernel(const short* __restrict__ x,
                                                   short* __restrict__ y,
                                                   const float* __restrict__ fr,
                                                   int N, float scale_base,
                                                   float sign, float prescale){
    int p = blockIdx.x * 256 + threadIdx.x;          // pair index
    int col2 = p & 511;                              // 512 pairs per row of D
    int row  = p >> 9;                               // b*N + n
    int n    = row & (N - 1);
    int i    = col2 & 31;                            // freq index within head
    float t  = (float)n;
    float fv = t * fr[i];
    float c = cosf(fv), s = sinf(fv);
    float power = (t - (float)(N / 2)) / scale_base;
    float sv = ((float)(2 * i) + 0.4f * 64.f) / (1.4f * 64.f);
    float scale = exp2f(sign * power * log2f(sv)) * prescale;
    unsigned xv = *(const unsigned*)(x + 2 * (size_t)p);
    float x0 = bf2f((unsigned short)(xv & 0xFFFFu));
    float x1 = bf2f((unsigned short)(xv >> 16));
    float y0 = (x0 * c - x1 * s) * scale;
    float y1 = (x1 * c + x0 * s) * scale;
    unsigned o = (unsigned)(unsigned short)f2bf(y0) |
                 ((unsigned)(unsigned short)f2bf(y1) << 16);
    *(unsigned*)(y + 2 * (size_t)p) = o;
}

// ---------------- GEMM: C(MxN) = A(MxK) * W(NxK)^T + bias ----------------
// 128x128 tile, 4 waves (2x2), BK=64, bf16 MFMA 16x16x32.
template<bool F32OUT>
__global__ __launch_bounds__(256) void gemm_bt(const short* __restrict__ A,
                                               const short* __restrict__ W,
                                               const float* __restrict__ bias,
                                               void* __restrict__ Cout,
                                               int M, int N, int K){
    __shared__ __align__(16) short lA[128 * 72];
    __shared__ __align__(16) short lB[128 * 72];
    int tid = threadIdx.x;
    int wave = tid >> 6, lane = tid & 63;
    int l16 = lane & 15, quad = lane >> 4;
    int wr = wave >> 1, wc = wave & 1;
    int row0 = blockIdx.y * 128, col0 = blockIdx.x * 128;

    f32x4 acc[4][4];
#pragma unroll
    for (int a = 0; a < 4; a++)
#pragma unroll
        for (int b = 0; b < 4; b++) acc[a][b] = (f32x4){0.f, 0.f, 0.f, 0.f};

    for (int k0 = 0; k0 < K; k0 += 64){
#pragma unroll
        for (int r = 0; r < 4; r++){
            int e = r * 2048 + tid * 8;
            int ar = e >> 6, ac = e & 63;
            *(uint4*)&lA[ar * 72 + ac] = *(const uint4*)(A + (size_t)(row0 + ar) * K + k0 + ac);
            *(uint4*)&lB[ar * 72 + ac] = *(const uint4*)(W + (size_t)(col0 + ar) * K + k0 + ac);
        }
        __syncthreads();
#pragma unroll
        for (int kk = 0; kk < 2; kk++){
            bf16x8 af[4], bfr[4];
#pragma unroll
            for (int t = 0; t < 4; t++){
                af[t]  = *(const bf16x8*)&lA[(wr * 64 + t * 16 + l16) * 72 + kk * 32 + quad * 8];
                bfr[t] = *(const bf16x8*)&lB[(wc * 64 + t * 16 + l16) * 72 + kk * 32 + quad * 8];
            }
#pragma unroll
            for (int tm = 0; tm < 4; tm++)
#pragma unroll
                for (int tn = 0; tn < 4; tn++)
                    acc[tm][tn] = __builtin_amdgcn_mfma_f32_16x16x32_bf16(af[tm], bfr[tn], acc[tm][tn], 0, 0, 0);
        }
        __syncthreads();
    }
#pragma unroll
    for (int tm = 0; tm < 4; tm++){
        int gr = row0 + wr * 64 + tm * 16 + quad * 4;
#pragma unroll
        for (int tn = 0; tn < 4; tn++){
            int gc = col0 + wc * 64 + tn * 16 + l16;
            float bv = bias[gc];
#pragma unroll
            for (int r = 0; r < 4; r++){
                float v = acc[tm][tn][r] + bv;
                if (F32OUT) ((float*)Cout)[(size_t)(gr + r) * N + gc] = v;
                else        ((short*)Cout)[(size_t)(gr + r) * N + gc] = f2bf(v);
            }
        }
    }
}

// ---------------- transpose V: (b,n,D) -> vT (b,h,hd,k) ----------------
__global__ __launch_bounds__(256) void transpose_v(const short* __restrict__ vp,
                                                   short* __restrict__ vT){
    int kt = blockIdx.x;      // 32 k-tiles
    int bh = blockIdx.y;      // b*H+h
    int b = bh >> 4, h = bh & 15;
    int tid = threadIdx.x;
    int hd = tid & 63;
#pragma unroll
    for (int it = 0; it < 16; it++){
        int kl = (tid >> 6) + it * 4;
        int k = kt * 64 + kl;
        short v = vp[((size_t)(b * NKK + k)) * DD + h * 64 + hd];
        vT[((size_t)(bh * 64 + hd)) * NKK + k] = v;
    }
}

// ---------------- fused attention (two-pass flash, attn materialized) ----
__global__ __launch_bounds__(256) void attn_kernel(const short* __restrict__ qp,
                                                   const short* __restrict__ kp,
                                                   const short* __restrict__ vT,
                                                   float* __restrict__ attn,
                                                   short* __restrict__ op){
    __shared__ __align__(16) short lK[64 * 72];
    __shared__ __align__(16) short lV[64 * 72];   // [hd][k]
    __shared__ __align__(16) short lP[64 * 72];   // [q][k]
    __shared__ float lMf[64], lLi[64];

    int qt = blockIdx.x;      // q tile (64 rows)
    int bh = blockIdx.y;
    int b = bh >> 4, h = bh & 15;
    int tid = threadIdx.x, wave = tid >> 6, lane = tid & 63;
    int l16 = lane & 15, quad = lane >> 4;

    int q0 = qt * 64;
    int qrow = q0 + wave * 16 + l16;
    const short* qb = qp + ((size_t)(b * NQ + qrow)) * DD + h * 64;
    bf16x8 qf[2];
    qf[0] = *(const bf16x8*)(qb + quad * 8);
    qf[1] = *(const bf16x8*)(qb + 32 + quad * 8);

    const short* kb = kp + ((size_t)(b * NKK)) * DD + h * 64;
    const short* vb = vT + ((size_t)(bh * 64)) * NKK;

    // -------- pass A: S^T = K*Q^T, online max/sum fully in-lane --------
    float m = -1e30f, l = 0.f;
    for (int kt = 0; kt < 32; kt++){
#pragma unroll
        for (int rnd = 0; rnd < 2; rnd++){
            int e = rnd * 2048 + tid * 8;
            int kr = e >> 6, kc = e & 63;
            *(uint4*)&lK[kr * 72 + kc] = *(const uint4*)(kb + (size_t)(kt * 64 + kr) * DD + kc);
        }
        __syncthreads();
        f32x4 St[4];
#pragma unroll
        for (int t = 0; t < 4; t++){
            f32x4 a = (f32x4){0.f, 0.f, 0.f, 0.f};
#pragma unroll
            for (int kk = 0; kk < 2; kk++){
                bf16x8 kf = *(const bf16x8*)&lK[(t * 16 + l16) * 72 + kk * 32 + quad * 8];
                a = __builtin_amdgcn_mfma_f32_16x16x32_bf16(kf, qf[kk], a, 0, 0, 0);
            }
            St[t] = a;
        }
        float mx = m;
#pragma unroll
        for (int t = 0; t < 4; t++)
#pragma unroll
            for (int r = 0; r < 4; r++) mx = fmaxf(mx, St[t][r]);
        float sum = 0.f;
#pragma unroll
        for (int t = 0; t < 4; t++)
#pragma unroll
            for (int r = 0; r < 4; r++) sum += __expf(St[t][r] - mx);
        l = l * __expf(m - mx) + sum;
        m = mx;
        __syncthreads();
    }
    // reduce across quads (each lane covered k = {16t + quad*4 + r})
    float M = fmaxf(m, __shfl_xor(m, 16, 64));
    M = fmaxf(M, __shfl_xor(M, 32, 64));
    float ls = l * __expf(m - M);
    ls += __shfl_xor(ls, 16, 64);
    ls += __shfl_xor(ls, 32, 64);
    if (quad == 0){ lMf[wave * 16 + l16] = M; lLi[wave * 16 + l16] = 1.f / ls; }
    __syncthreads();
    float mf[4], il[4];
#pragma unroll
    for (int r = 0; r < 4; r++){
        mf[r] = lMf[wave * 16 + quad * 4 + r];
        il[r] = lLi[wave * 16 + quad * 4 + r];
    }

    // -------- pass B: S normal orientation, write attn, O += P*V --------
    f32x4 O[4];
#pragma unroll
    for (int th = 0; th < 4; th++) O[th] = (f32x4){0.f, 0.f, 0.f, 0.f};
    float* ab = attn + (((size_t)bh * NQ) + q0 + wave * 16) * NKK;

    for (int kt = 0; kt < 32; kt++){
#pragma unroll
        for (int rnd = 0; rnd < 2; rnd++){
            int e = rnd * 2048 + tid * 8;
            int kr = e >> 6, kc = e & 63;
            *(uint4*)&lK[kr * 72 + kc] = *(const uint4*)(kb + (size_t)(kt * 64 + kr) * DD + kc);
            *(uint4*)&lV[kr * 72 + kc] = *(const uint4*)(vb + (size_t)kr * NKK + kt * 64 + kc);
        }
        __syncthreads();
        f32x4 S[4];
#pragma unroll
        for (int tn = 0; tn < 4; tn++){
            f32x4 a = (f32x4){0.f, 0.f, 0.f, 0.f};
#pragma unroll
            for (int kk = 0; kk < 2; kk++){
                bf16x8 kf = *(const bf16x8*)&lK[(tn * 16 + l16) * 72 + kk * 32 + quad * 8];
                a = __builtin_amdgcn_mfma_f32_16x16x32_bf16(qf[kk], kf, a, 0, 0, 0);
            }
            S[tn] = a;
        }
#pragma unroll
        for (int tn = 0; tn < 4; tn++){
#pragma unroll
            for (int r = 0; r < 4; r++){
                float p = __expf(S[tn][r] - mf[r]) * il[r];
                ab[(size_t)(quad * 4 + r) * NKK + kt * 64 + tn * 16 + l16] = p;
                lP[(wave * 16 + quad * 4 + r) * 72 + tn * 16 + l16] = f2bf(p);
            }
        }
        // wave-private LDS strip: ds ordering handled by lgkmcnt, no barrier
#pragma unroll
        for (int kk = 0; kk < 2; kk++){
            bf16x8 pf = *(const bf16x8*)&lP[(wave * 16 + l16) * 72 + kk * 32 + quad * 8];
#pragma unroll
            for (int th = 0; th < 4; th++){
                bf16x8 vf = *(const bf16x8*)&lV[(th * 16 + l16) * 72 + kk * 32 + quad * 8];
                O[th] = __builtin_amdgcn_mfma_f32_16x16x32_bf16(pf, vf, O[th], 0, 0, 0);
            }
        }
        __syncthreads();
    }
    // epilogue: O -> op (b, q, h*64+hd) bf16
#pragma unroll
    for (int th = 0; th < 4; th++){
#pragma unroll
        for (int r = 0; r < 4; r++){
            int q = q0 + wave * 16 + quad * 4 + r;
            op[((size_t)(b * NQ + q)) * DD + h * 64 + th * 16 + l16] = f2bf(O[th][r]);
        }
    }
}

extern "C" void kernel_launch(void* const* d_in, const int* in_sizes, int n_in,
                              void* d_out, int out_size, void* d_ws, size_t ws_size,
                              hipStream_t stream) {
    const float* q_seq = (const float*)d_in[0];
    const float* kv_seq = (const float*)d_in[1];
    const float* Wq = (const float*)d_in[2];
    const float* bq = (const float*)d_in[3];
    const float* Wk = (const float*)d_in[4];
    const float* bk = (const float*)d_in[5];
    const float* Wv = (const float*)d_in[6];
    const float* bv = (const float*)d_in[7];
    const float* Wo = (const float*)d_in[8];
    const float* bo = (const float*)d_in[9];
    const float* freqs_q = (const float*)d_in[10];
    const float* freqs_kv = (const float*)d_in[11];

    float* out0 = (float*)d_out;                     // (B, NQ, D)
    float* attn = (float*)d_out + 4194304;           // (B, H, NQ, NK)

    // workspace layout (bf16 shorts)
    short* qb  = (short*)d_ws;          // 4194304  q_seq bf16
    short* kvb = qb  + 4194304;         // 4194304  kv_seq bf16
    short* wqb = kvb + 4194304;         // 1048576
    short* wkb = wqb + 1048576;
    short* wvb = wkb + 1048576;
    short* wob = wvb + 1048576;
    short* tmp = wob + 1048576;         // 4194304  pre-rope proj / O
    short* qpb = tmp + 4194304;         // 4194304  q post-rope
    short* kpb = qpb + 4194304;         // 4194304  k post-rope
    short* vpb = kpb + 4194304;         // 4194304  v
    short* vTb = qb;                    // alias: q_seq bf16 dead after GEMM_Q
    short* opb = tmp;                   // alias: tmp dead after rope_k

    // 1) conversions
    cvt_bf16<<<4096, 256, 0, stream>>>(q_seq, qb, 4194304);
    cvt_bf16<<<4096, 256, 0, stream>>>(kv_seq, kvb, 4194304);
    cvt_bf16<<<1024, 256, 0, stream>>>(Wq, wqb, 1048576);
    cvt_bf16<<<1024, 256, 0, stream>>>(Wk, wkb, 1048576);
    cvt_bf16<<<1024, 256, 0, stream>>>(Wv, wvb, 1048576);
    cvt_bf16<<<1024, 256, 0, stream>>>(Wo, wob, 1048576);

    dim3 ggrid(8, 32);   // N/128, M/128
    // 2) Q proj -> rope(+fold 1/sqrt(HD)=0.125)
    gemm_bt<false><<<ggrid, 256, 0, stream>>>(qb, wqb, bq, tmp, 4096, 1024, 1024);
    rope_kernel<<<8192, 256, 0, stream>>>(tmp, qpb, freqs_q, NQ, 4096.f, 1.f, 0.125f);
    // 3) K proj -> rope (sign -1)
    gemm_bt<false><<<ggrid, 256, 0, stream>>>(kvb, wkb, bk, tmp, 4096, 1024, 1024);
    rope_kernel<<<8192, 256, 0, stream>>>(tmp, kpb, freqs_kv, NKK, 4096.f, -1.f, 1.f);
    // 4) V proj, transpose
    gemm_bt<false><<<ggrid, 256, 0, stream>>>(kvb, wvb, bv, vpb, 4096, 1024, 1024);
    transpose_v<<<dim3(32, 32), 256, 0, stream>>>(vpb, vTb);
    // 5) attention
    attn_kernel<<<dim3(32, 32), 256, 0, stream>>>(qpb, kpb, vTb, attn, opb);
    // 6) out projection (fp32 out)
    gemm_bt<true><<<ggrid, 256, 0, stream>>>(opb, wob, bo, out0, 4096, 1024, 1024);
}